// Round 1
// baseline (85.465 us; speedup 1.0000x reference)
//
#include <hip/hip_runtime.h>

// SelfAttention with 1x1 convs on C=1: q,k,v are scalar affines of x.
// scores[b,i,j] = q_i * k_j  ->  softmax row i == softmax_j(t_i * x_j),
// t_i = (wq*x_i+bq)*wk, row max analytic from per-batch xmax/xmin.
// out_i = (wv*W + bv*S)/S with S=sum_j e_ij, W=sum_j e_ij*x_j.

#define N_TOK   4096
#define THREADS 256
#define I_PER_BLK 32            // rows per block (THREADS/8)
#define JS      8               // j-split threads per row
#define LOG2E   1.4426950408889634f

__device__ __forceinline__ float fast_exp2(float v) {
#if defined(__has_builtin)
#if __has_builtin(__builtin_amdgcn_exp2f)
    return __builtin_amdgcn_exp2f(v);
#else
    return exp2f(v);
#endif
#else
    return exp2f(v);
#endif
}

__global__ __launch_bounds__(THREADS) void SelfAttention_43284680409543_kernel(
    const float* __restrict__ x,
    const float* __restrict__ pwq, const float* __restrict__ pbq,
    const float* __restrict__ pwk, const float* __restrict__ pbk,
    const float* __restrict__ pwv, const float* __restrict__ pbv,
    const float* __restrict__ pgamma,
    float* __restrict__ out)
{
    __shared__ float sx[N_TOK];
    __shared__ float sred[8];           // [0..3] wave maxes, [4..7] wave mins

    const int tid  = threadIdx.x;
    const int bidx = blockIdx.x;
    const int b    = bidx & 7;          // batch (interleaved for XCD spread)
    const int blk  = bidx >> 3;         // row-chunk within batch

    // ---- stage x[b,:] into LDS (float4), tracking local max/min ----
    const float4* x4  = reinterpret_cast<const float4*>(x + b * N_TOK);
    float4*       sx4 = reinterpret_cast<float4*>(sx);
    float mx = -__builtin_inff(), mn = __builtin_inff();
#pragma unroll
    for (int k = 0; k < 4; ++k) {
        float4 v = x4[tid + k * THREADS];
        sx4[tid + k * THREADS] = v;
        mx = fmaxf(mx, fmaxf(fmaxf(v.x, v.y), fmaxf(v.z, v.w)));
        mn = fminf(mn, fminf(fminf(v.x, v.y), fminf(v.z, v.w)));
    }
    // wave64 reduce
#pragma unroll
    for (int d = 32; d >= 1; d >>= 1) {
        mx = fmaxf(mx, __shfl_down(mx, d, 64));
        mn = fminf(mn, __shfl_down(mn, d, 64));
    }
    const int wave = tid >> 6;
    if ((tid & 63) == 0) { sred[wave] = mx; sred[4 + wave] = mn; }
    __syncthreads();
    const float xmax = fmaxf(fmaxf(sred[0], sred[1]), fmaxf(sred[2], sred[3]));
    const float xmin = fminf(fminf(sred[4], sred[5]), fminf(sred[6], sred[7]));

    // scalar params (single-address loads, L2-broadcast)
    const float wq = *pwq, bq = *pbq, wk = *pwk;
    const float wv = *pwv, bv = *pbv, gamma = *pgamma;

    // ---- per-row setup: 8 threads per row ----
    const int i_local = tid >> 3;       // 0..31
    const int js      = tid & 7;        // 0..7
    const int i       = blk * I_PER_BLK + i_local;

    const float xi = sx[i];
    const float q  = fmaf(wq, xi, bq);
    const float t  = q * wk;
    const float m  = (t >= 0.f) ? t * xmax : t * xmin;  // analytic row max of t*x_j
    const float a  = t * LOG2E;
    const float c  = m * LOG2E;

    // ---- main loop: each thread covers 512 j's as 128 float4 chunks ----
    // wave pattern: 8 distinct 16B addresses spanning exactly 32 banks -> conflict-free
    const float4* sxv = reinterpret_cast<const float4*>(sx);
    float S = 0.f, W = 0.f;
#pragma unroll 4
    for (int jj = 0; jj < N_TOK / (JS * 4); ++jj) {
        float4 xj = sxv[jj * JS + js];
        float e0 = fast_exp2(fmaf(a, xj.x, -c));
        float e1 = fast_exp2(fmaf(a, xj.y, -c));
        float e2 = fast_exp2(fmaf(a, xj.z, -c));
        float e3 = fast_exp2(fmaf(a, xj.w, -c));
        S += e0; W = fmaf(e0, xj.x, W);
        S += e1; W = fmaf(e1, xj.y, W);
        S += e2; W = fmaf(e2, xj.z, W);
        S += e3; W = fmaf(e3, xj.w, W);
    }

    // ---- reduce S, W across the 8 cooperating lanes (consecutive) ----
#pragma unroll
    for (int d = 4; d >= 1; d >>= 1) {
        S += __shfl_down(S, d, 8);
        W += __shfl_down(W, d, 8);
    }

    if (js == 0) {
        const float num = fmaf(wv, W, bv * S);   // sum_j e_ij * v_j
        const float o   = num / S;               // attention output
        out[b * N_TOK + i] = fmaf(gamma, o, xi); // gamma*out + x
    }
}

extern "C" void kernel_launch(void* const* d_in, const int* in_sizes, int n_in,
                              void* d_out, int out_size, void* d_ws, size_t ws_size,
                              hipStream_t stream) {
    const float* x = (const float*)d_in[0];
    SelfAttention_43284680409543_kernel<<<dim3(8 * (N_TOK / I_PER_BLK)), dim3(THREADS), 0, stream>>>(
        x,
        (const float*)d_in[1], (const float*)d_in[2],
        (const float*)d_in[3], (const float*)d_in[4],
        (const float*)d_in[5], (const float*)d_in[6],
        (const float*)d_in[7],
        (float*)d_out);
}

// Round 2
// 71.217 us; speedup vs baseline: 1.2001x; 1.2001x over previous
//
#include <hip/hip_runtime.h>

// SelfAttention, C=1: q,k,v are scalar affines of x.
// Row i of softmax(q_i k_j) depends only on t_i = (wq*x_i+bq)*wk:
//   out_i = gamma*(wv*g(t_i)+bv) + x_i,  g(t) = sum_j x_j e^{t x_j} / sum_j e^{t x_j}.
// g is the derivative of the log-partition: smooth & analytic -> Chebyshev-Lobatto
// interpolation with K=64 nodes over the exact runtime t-range is accurate to
// ~1e-20 (superexponential convergence for entire integrands).
// Phase A: exact g at 64 nodes per batch (8x64 blocks, N exps each).
// Phase B: barycentric evaluation per row (rcp instead of exp).

#define N_TOK   4096
#define NB      8
#define KN      64
#define THREADS 256
#define LOG2E   1.4426950408889634f
#define PI_F    3.14159265358979323846f

__device__ __forceinline__ float fast_exp2(float v) { return __builtin_amdgcn_exp2f(v); }
__device__ __forceinline__ float fast_rcp(float v)  { return __builtin_amdgcn_rcpf(v); }

// ---------------- Phase A: per-(batch,node) exact softmax-weighted mean ----------------
__global__ __launch_bounds__(THREADS) void SelfAttention_nodes_kernel(
    const float* __restrict__ x,
    const float* __restrict__ pwq, const float* __restrict__ pbq,
    const float* __restrict__ pwk,
    float* __restrict__ tab)          // [NB][KN][3] = { t_k, w_k, w_k * g_k }
{
    __shared__ float sx[N_TOK];
    __shared__ float sred[16];        // [0..3] max, [4..7] min, [8..11] S, [12..15] W

    const int tid = threadIdx.x;
    const int b   = blockIdx.x & (NB - 1);   // batch
    const int k   = blockIdx.x >> 3;         // node index 0..KN-1

    // stage x[b,:] into LDS, tracking min/max (min/max are exactly associative,
    // so every block of this batch derives identical xmin/xmax)
    const float4* x4  = reinterpret_cast<const float4*>(x + b * N_TOK);
    float4*       sx4 = reinterpret_cast<float4*>(sx);
    float mx = -__builtin_inff(), mn = __builtin_inff();
#pragma unroll
    for (int q = 0; q < 4; ++q) {
        float4 v = x4[tid + q * THREADS];
        sx4[tid + q * THREADS] = v;
        mx = fmaxf(mx, fmaxf(fmaxf(v.x, v.y), fmaxf(v.z, v.w)));
        mn = fminf(mn, fminf(fminf(v.x, v.y), fminf(v.z, v.w)));
    }
#pragma unroll
    for (int d = 32; d >= 1; d >>= 1) {
        mx = fmaxf(mx, __shfl_down(mx, d, 64));
        mn = fminf(mn, __shfl_down(mn, d, 64));
    }
    const int wave = tid >> 6;
    if ((tid & 63) == 0) { sred[wave] = mx; sred[4 + wave] = mn; }
    __syncthreads();
    const float xmax = fmaxf(fmaxf(sred[0], sred[1]), fmaxf(sred[2], sred[3]));
    const float xmin = fminf(fminf(sred[4], sred[5]), fminf(sred[6], sred[7]));

    const float wq = *pwq, bq = *pbq, wk = *pwk;

    // t-range over x in [xmin,xmax] (affine -> endpoints), slightly padded
    const float e1  = fmaf(wq, xmin, bq) * wk;
    const float e2  = fmaf(wq, xmax, bq) * wk;
    const float tlo = fminf(e1, e2), thi = fmaxf(e1, e2);
    const float cc  = 0.5f * (tlo + thi);
    const float rr  = 0.5f * (thi - tlo) * 1.0001f + 1e-7f;

    // Chebyshev-Lobatto node k
    const float tk = cc + rr * cosf(PI_F * (float)k / (float)(KN - 1));

    // stable exp: shift by exact max of tk*x over [xmin,xmax]
    const float m = fmaxf(tk * xmax, tk * xmin);
    const float a = tk * LOG2E;
    const float c = m  * LOG2E;

    const float4* sxv = reinterpret_cast<const float4*>(sx);
    float S = 0.f, W = 0.f;
#pragma unroll
    for (int q = 0; q < 4; ++q) {
        float4 xj = sxv[tid + q * THREADS];
        float t0 = fast_exp2(fmaf(a, xj.x, -c));
        float t1 = fast_exp2(fmaf(a, xj.y, -c));
        float t2 = fast_exp2(fmaf(a, xj.z, -c));
        float t3 = fast_exp2(fmaf(a, xj.w, -c));
        S += t0; W = fmaf(t0, xj.x, W);
        S += t1; W = fmaf(t1, xj.y, W);
        S += t2; W = fmaf(t2, xj.z, W);
        S += t3; W = fmaf(t3, xj.w, W);
    }
#pragma unroll
    for (int d = 32; d >= 1; d >>= 1) {
        S += __shfl_down(S, d, 64);
        W += __shfl_down(W, d, 64);
    }
    if ((tid & 63) == 0) { sred[8 + wave] = S; sred[12 + wave] = W; }
    __syncthreads();
    if (tid == 0) {
        const float St = sred[8] + sred[9] + sred[10] + sred[11];
        const float Wt = sred[12] + sred[13] + sred[14] + sred[15];
        const float g  = Wt / St;                         // in [xmin,xmax], finite (S>=1)
        float wgt = (k == 0 || k == KN - 1) ? 0.5f : 1.0f;
        if (k & 1) wgt = -wgt;
        float* e = tab + (b * KN + k) * 3;
        e[0] = tk; e[1] = wgt; e[2] = wgt * g;
    }
}

// ---------------- Phase B: barycentric interpolation per row ----------------
__global__ __launch_bounds__(THREADS) void SelfAttention_rows_kernel(
    const float* __restrict__ x,
    const float* __restrict__ pwq, const float* __restrict__ pbq,
    const float* __restrict__ pwk,
    const float* __restrict__ pwv, const float* __restrict__ pbv,
    const float* __restrict__ pgamma,
    const float* __restrict__ tab,
    float* __restrict__ out)
{
    __shared__ float st[KN], sw[KN], swg[KN];

    const int tid = threadIdx.x;
    const int b   = blockIdx.x & (NB - 1);
    const int blk = blockIdx.x >> 3;

    if (tid < KN) {
        const float* e = tab + (b * KN + tid) * 3;
        st[tid] = e[0]; sw[tid] = e[1]; swg[tid] = e[2];
    }
    __syncthreads();

    const float wq = *pwq, bq = *pbq, wk = *pwk;
    const float wv = *pwv, bv = *pbv, gamma = *pgamma;

    const int   i  = blk * THREADS + tid;
    const float xi = x[b * N_TOK + i];
    const float t  = fmaf(wq, xi, bq) * wk;

    float num = 0.f, den = 0.f;
#pragma unroll 16
    for (int k = 0; k < KN; ++k) {
        float d = t - st[k];
        d = copysignf(fmaxf(fabsf(d), 1e-12f), d);   // node-coincidence guard
        const float u = fast_rcp(d);
        num = fmaf(u, swg[k], num);
        den = fmaf(u, sw[k], den);
    }
    const float g = num * fast_rcp(den);
    const float o = fmaf(wv, g, bv);
    out[b * N_TOK + i] = fmaf(gamma, o, xi);
}

extern "C" void kernel_launch(void* const* d_in, const int* in_sizes, int n_in,
                              void* d_out, int out_size, void* d_ws, size_t ws_size,
                              hipStream_t stream) {
    const float* x = (const float*)d_in[0];
    float* tab = (float*)d_ws;   // NB*KN*3 floats = 6 KB

    SelfAttention_nodes_kernel<<<dim3(NB * KN), dim3(THREADS), 0, stream>>>(
        x, (const float*)d_in[1], (const float*)d_in[2], (const float*)d_in[3], tab);

    SelfAttention_rows_kernel<<<dim3(NB * (N_TOK / THREADS)), dim3(THREADS), 0, stream>>>(
        x, (const float*)d_in[1], (const float*)d_in[2], (const float*)d_in[3],
        (const float*)d_in[5], (const float*)d_in[6], (const float*)d_in[7],
        tab, (float*)d_out);
}

// Round 3
// 70.694 us; speedup vs baseline: 1.2089x; 1.0074x over previous
//
#include <hip/hip_runtime.h>

// SelfAttention, C=1: q,k,v are scalar affines of x.
//   out_i = gamma*(wv*g(t_i)+bv) + x_i,  t_i=(wq*x_i+bq)*wk,
//   g(t) = sum_j x_j e^{t x_j} / sum_j e^{t x_j}   (log-partition derivative).
// g is analytic -> 64-node Chebyshev-Lobatto barycentric interp over the exact
// runtime t-range (error ~1e-20, superexponential convergence).
// Phase A: exact g at 64 nodes/batch. One wave per (batch,node): x in VGPRs,
//          shfl_xor butterflies, no LDS, no syncthreads.
// Phase B: barycentric eval per row, one wave per 64 rows, table in LDS float4.

#define N_TOK   4096
#define NB      8
#define KN      64
#define LOG2E   1.4426950408889634f
#define PI_F    3.14159265358979323846f

__device__ __forceinline__ float fast_exp2(float v) { return __builtin_amdgcn_exp2f(v); }
__device__ __forceinline__ float fast_rcp(float v)  { return __builtin_amdgcn_rcpf(v); }

// ---------------- Phase A: one wave per (batch, node) ----------------
__global__ __launch_bounds__(64) void SelfAttention_nodes_kernel(
    const float* __restrict__ x,
    const float* __restrict__ pwq, const float* __restrict__ pbq,
    const float* __restrict__ pwk,
    float4* __restrict__ tab)          // [NB][KN] = { t_k, w_k, w_k*g_k, 0 }
{
    const int lane = threadIdx.x;            // 0..63
    const int b    = blockIdx.x & (NB - 1);  // batch
    const int k    = blockIdx.x >> 3;        // node 0..KN-1

    // load 64 floats/lane into registers (16 x float4, coalesced)
    const float4* x4 = reinterpret_cast<const float4*>(x + b * N_TOK);
    float4 v[16];
    float mx = -__builtin_inff(), mn = __builtin_inff();
#pragma unroll
    for (int q = 0; q < 16; ++q) {
        v[q] = x4[lane + q * 64];
        mx = fmaxf(mx, fmaxf(fmaxf(v[q].x, v[q].y), fmaxf(v[q].z, v[q].w)));
        mn = fminf(mn, fminf(fminf(v[q].x, v[q].y), fminf(v[q].z, v[q].w)));
    }
    // butterfly: every lane ends with the global min/max (exactly associative)
#pragma unroll
    for (int m = 32; m >= 1; m >>= 1) {
        mx = fmaxf(mx, __shfl_xor(mx, m, 64));
        mn = fminf(mn, __shfl_xor(mn, m, 64));
    }

    const float wq = *pwq, bq = *pbq, wk = *pwk;

    // t-range (affine in x -> endpoints), slightly padded
    const float e1  = fmaf(wq, mn, bq) * wk;
    const float e2  = fmaf(wq, mx, bq) * wk;
    const float tlo = fminf(e1, e2), thi = fmaxf(e1, e2);
    const float cc  = 0.5f * (tlo + thi);
    const float rr  = 0.5f * (thi - tlo) * 1.0001f + 1e-7f;

    const float tk = cc + rr * cosf(PI_F * (float)k / (float)(KN - 1));

    // stable shift: exact max of tk*x over [mn,mx]
    const float mshift = fmaxf(tk * mx, tk * mn);
    const float a = tk * LOG2E;
    const float c = mshift * LOG2E;

    float S = 0.f, W = 0.f;
#pragma unroll
    for (int q = 0; q < 16; ++q) {
        float t0 = fast_exp2(fmaf(a, v[q].x, -c));
        float t1 = fast_exp2(fmaf(a, v[q].y, -c));
        float t2 = fast_exp2(fmaf(a, v[q].z, -c));
        float t3 = fast_exp2(fmaf(a, v[q].w, -c));
        S += t0; W = fmaf(t0, v[q].x, W);
        S += t1; W = fmaf(t1, v[q].y, W);
        S += t2; W = fmaf(t2, v[q].z, W);
        S += t3; W = fmaf(t3, v[q].w, W);
    }
#pragma unroll
    for (int m = 32; m >= 1; m >>= 1) {
        S += __shfl_xor(S, m, 64);
        W += __shfl_xor(W, m, 64);
    }

    if (lane == 0) {
        const float g = W / S;                       // finite: S >= 1 (max term = 1)
        float wgt = (k == 0 || k == KN - 1) ? 0.5f : 1.0f;
        if (k & 1) wgt = -wgt;
        tab[b * KN + k] = make_float4(tk, wgt, wgt * g, 0.f);
    }
}

// ---------------- Phase B: one wave per 64 rows ----------------
__global__ __launch_bounds__(64) void SelfAttention_rows_kernel(
    const float* __restrict__ x,
    const float* __restrict__ pwq, const float* __restrict__ pbq,
    const float* __restrict__ pwk,
    const float* __restrict__ pwv, const float* __restrict__ pbv,
    const float* __restrict__ pgamma,
    const float4* __restrict__ tab,
    float* __restrict__ out)
{
    __shared__ float4 stab[KN];

    const int lane = threadIdx.x;
    const int b    = blockIdx.x & (NB - 1);
    const int blk  = blockIdx.x >> 3;        // 0..63

    stab[lane] = tab[b * KN + lane];         // 64 lanes load 64 entries
    __syncthreads();

    const float wq = *pwq, bq = *pbq, wk = *pwk;
    const float wv = *pwv, bv = *pbv, gamma = *pgamma;

    const int   i  = blk * 64 + lane;
    const float xi = x[b * N_TOK + i];
    const float t  = fmaf(wq, xi, bq) * wk;

    float num = 0.f, den = 0.f;
#pragma unroll 16
    for (int k = 0; k < KN; ++k) {
        const float4 e = stab[k];            // same addr across wave: broadcast
        float d = t - e.x;
        d = copysignf(fmaxf(fabsf(d), 1e-12f), d);   // node-coincidence guard
        const float u = fast_rcp(d);
        num = fmaf(u, e.z, num);
        den = fmaf(u, e.y, den);
    }
    const float g = num * fast_rcp(den);
    const float o = fmaf(wv, g, bv);
    out[b * N_TOK + i] = fmaf(gamma, o, xi);
}

extern "C" void kernel_launch(void* const* d_in, const int* in_sizes, int n_in,
                              void* d_out, int out_size, void* d_ws, size_t ws_size,
                              hipStream_t stream) {
    const float* x = (const float*)d_in[0];
    float4* tab = (float4*)d_ws;   // NB*KN*16 B = 8 KB

    SelfAttention_nodes_kernel<<<dim3(NB * KN), dim3(64), 0, stream>>>(
        x, (const float*)d_in[1], (const float*)d_in[2], (const float*)d_in[3], tab);

    SelfAttention_rows_kernel<<<dim3(NB * (N_TOK / 64)), dim3(64), 0, stream>>>(
        x, (const float*)d_in[1], (const float*)d_in[2], (const float*)d_in[3],
        (const float*)d_in[5], (const float*)d_in[6], (const float*)d_in[7],
        tab, (float*)d_out);
}